// Round 6
// baseline (401.882 us; speedup 1.0000x reference)
//
#include <hip/hip_runtime.h>
#include <cstddef>

#define LQ 1024
#define DM 128
#define DI 256
#define DSN 16
#define NB 8
#define ROWS (NB*LQ)
#define EPSF 1e-5f
#define CHUNK 32
#define NCHUNK (LQ/CHUNK)

typedef _Float16 f16;
typedef __attribute__((ext_vector_type(8))) _Float16 f16x8;
typedef __attribute__((ext_vector_type(4))) _Float16 f16x4;
typedef __attribute__((ext_vector_type(4))) float f32x4;

static __device__ __forceinline__ float sigmoid_f(float x) { return 1.f/(1.f+__expf(-x)); }
static __device__ __forceinline__ float softplus_f(float x) {
  return (x > 20.f) ? x : log1pf(__expf(x));
}

// ---------------- one-shot fp32 -> fp16 conversion of all three weight sets ----------------
__global__ __launch_bounds__(256) void cvt_all(
    const float* __restrict__ a, const float* __restrict__ bsrc, const float* __restrict__ csrc,
    f16* __restrict__ oa, f16* __restrict__ ob, f16* __restrict__ oc)
{
  int i = blockIdx.x*256 + threadIdx.x;
  const int na = (4*2*DI*DM)/4;
  const int nb = (4*40*DI)/4;
  const int nc = (4*DM*DI)/4;
  const float* s; f16* o; int k;
  if (i < na)            { s = a;    o = oa; k = i; }
  else if (i < na+nb)    { s = bsrc; o = ob; k = i - na; }
  else if (i < na+nb+nc) { s = csrc; o = oc; k = i - na - nb; }
  else return;
  float4 v = ((const float4*)s)[k];
  f16x4 r; r.x=(f16)v.x; r.y=(f16)v.y; r.z=(f16)v.z; r.w=(f16)v.w;
  ((f16x4*)o)[k] = r;
}

// ============ K_A: rmsnorm + in_proj(x, halo) + conv/silu + x_proj + scan p1 ============
// block = (batch, 32-chunk), 1024 threads = 16 waves
__global__ __launch_bounds__(1024) void layer_front(
    const float* __restrict__ src, const float* __restrict__ nw,
    const f16* __restrict__ Win, const float* __restrict__ cw, const float* __restrict__ cb,
    const f16* __restrict__ xpw, const float* __restrict__ A_log,
    const float* __restrict__ dtw, const float* __restrict__ dtb,
    f16* __restrict__ xs_out, float* __restrict__ dbc_out,
    float* __restrict__ S, float* __restrict__ sumdl_out)
{
  __shared__ __align__(16) f16 Ah[48][136];
  __shared__ __align__(16) f16 sXc[48][264];
  __shared__ __align__(16) f16 sXs[32][264];
  __shared__ __align__(16) float sDbc[32][40];
  const int bc = blockIdx.x;
  const int b = bc >> 5, ck = bc & (NCHUNK-1);
  const int t0 = ck*CHUNK;
  const int tid = threadIdx.x;
  const int l = tid & 63, w = tid >> 6;
  const int fr = l & 15, kg = l >> 4;

  // --- stage Ah with fused rmsnorm: 16 lanes per row, rows 0..47 (t0-3..t0+31, tail zero) ---
  {
    const int r = tid >> 4;            // 0..63
    const int seg = (tid & 15) * 8;
    float4 v0 = make_float4(0,0,0,0), v1 = v0;
    const bool valid = (r < 35) && (ck > 0 || r >= 3);
    float ss = 0.f;
    if (valid) {
      const float* hr = src + (size_t)(b*LQ + t0 - 3 + r)*DM + seg;
      v0 = *(const float4*)(hr);
      v1 = *(const float4*)(hr + 4);
      ss = v0.x*v0.x+v0.y*v0.y+v0.z*v0.z+v0.w*v0.w + v1.x*v1.x+v1.y*v1.y+v1.z*v1.z+v1.w*v1.w;
    }
    ss += __shfl_xor(ss, 1); ss += __shfl_xor(ss, 2);
    ss += __shfl_xor(ss, 4); ss += __shfl_xor(ss, 8);
    if (r < 48) {
      f16x4 o0 = (f16x4){0,0,0,0}, o1 = o0;
      if (valid) {
        const float sc = rsqrtf(ss*(1.f/128.f) + EPSF);
        float4 w0 = *(const float4*)(nw + seg);
        float4 w1 = *(const float4*)(nw + seg + 4);
        o0.x=(f16)(v0.x*sc*w0.x); o0.y=(f16)(v0.y*sc*w0.y); o0.z=(f16)(v0.z*sc*w0.z); o0.w=(f16)(v0.w*sc*w0.w);
        o1.x=(f16)(v1.x*sc*w1.x); o1.y=(f16)(v1.y*sc*w1.y); o1.z=(f16)(v1.z*sc*w1.z); o1.w=(f16)(v1.w*sc*w1.w);
      }
      *(f16x4*)&Ah[r][seg] = o0;
      *(f16x4*)&Ah[r][seg+4] = o1;
    }
  }
  __syncthreads();

  // --- in_proj x-half MFMA: sXc[48][256] = Ah @ Win_x^T; wave w -> cols w*16..+15 ---
  {
    f32x4 acc[3];
    #pragma unroll
    for (int m = 0; m < 3; ++m) acc[m] = (f32x4){0.f,0.f,0.f,0.f};
    #pragma unroll
    for (int s = 0; s < 4; ++s) {
      f16x8 bfv = *(const f16x8*)(Win + (size_t)(w*16 + fr)*DM + s*32 + kg*8);
      #pragma unroll
      for (int m = 0; m < 3; ++m) {
        f16x8 afv = *(const f16x8*)&Ah[m*16 + fr][s*32 + kg*8];
        acc[m] = __builtin_amdgcn_mfma_f32_16x16x32_f16(afv, bfv, acc[m], 0, 0, 0);
      }
    }
    #pragma unroll
    for (int m = 0; m < 3; ++m)
      #pragma unroll
      for (int j = 0; j < 4; ++j)
        sXc[m*16 + kg*4 + j][w*16 + fr] = (f16)acc[m][j];
  }
  __syncthreads();

  // --- conv + silu: thread = (d, 8-step group) ---
  {
    const int d = tid & 255, tq = tid >> 8;
    const float4 cwv = *(const float4*)(cw + d*4);
    const float bias = cb[d];
    #pragma unroll
    for (int i = 0; i < 8; ++i) {
      int t = tq*8 + i;
      float a = bias + (float)sXc[t][d]*cwv.x + (float)sXc[t+1][d]*cwv.y
                     + (float)sXc[t+2][d]*cwv.z + (float)sXc[t+3][d]*cwv.w;
      float sv = a * sigmoid_f(a);
      f16 s16 = (f16)sv;
      sXs[t][d] = s16;
      xs_out[(size_t)(b*LQ + t0 + t)*DI + d] = s16;
    }
  }
  __syncthreads();

  // --- x_proj MFMA: dbc[32][40]; waves 0..5 = (2 M) x (3 N) ---
  if (w < 6) {
    const int mi = w & 1, ni = w >> 1;
    const int col = ni*16 + fr;
    f32x4 acc = (f32x4){0.f,0.f,0.f,0.f};
    #pragma unroll
    for (int s = 0; s < 8; ++s) {
      f16x8 bfv = (f16x8){0,0,0,0,0,0,0,0};
      if (col < 40) bfv = *(const f16x8*)(xpw + (size_t)col*DI + s*32 + kg*8);
      f16x8 afv = *(const f16x8*)&sXs[mi*16 + fr][s*32 + kg*8];
      acc = __builtin_amdgcn_mfma_f32_16x16x32_f16(afv, bfv, acc, 0, 0, 0);
    }
    if (col < 40) {
      #pragma unroll
      for (int j = 0; j < 4; ++j) {
        int row = mi*16 + kg*4 + j;
        sDbc[row][col] = acc[j];
        dbc_out[(size_t)(b*LQ + t0 + row)*40 + col] = acc[j];
      }
    }
  }
  __syncthreads();

  // --- scan p1: thread = (d, 4-state group g) ---
  {
    const int d = tid >> 2, g = tid & 3;
    float A[4];
    #pragma unroll
    for (int j = 0; j < 4; ++j) A[j] = -__expf(A_log[d*16 + g*4 + j]);
    const float4 dw0 = *(const float4*)(dtw + d*8);
    const float4 dw1 = *(const float4*)(dtw + d*8 + 4);
    const float bt = dtb[d];
    float h[4] = {};
    float sdl = 0.f;
    for (int t = 0; t < CHUNK; ++t) {
      float xa = bt + sDbc[t][0]*dw0.x + sDbc[t][1]*dw0.y + sDbc[t][2]*dw0.z + sDbc[t][3]*dw0.w
                    + sDbc[t][4]*dw1.x + sDbc[t][5]*dw1.y + sDbc[t][6]*dw1.z + sDbc[t][7]*dw1.w;
      float dl = softplus_f(xa);
      float du = dl * (float)sXs[t][d];
      sdl += dl;
      #pragma unroll
      for (int j = 0; j < 4; ++j)
        h[j] = __expf(dl*A[j])*h[j] + du*sDbc[t][8 + g*4 + j];
    }
    *(float4*)(S + ((size_t)bc*DI + d)*16 + g*4) = make_float4(h[0],h[1],h[2],h[3]);
    if (g == 0) sumdl_out[(size_t)bc*DI + d] = sdl;
  }
}

// ============ K_B: exclusive scan over chunks (in-place S -> Hinit) ============
__global__ __launch_bounds__(256) void scan_p2(
    float* __restrict__ S, const float* __restrict__ sumdl,
    const float* __restrict__ A_log)
{
  int g = blockIdx.x*256 + threadIdx.x;   // b*4096 + d*16 + n
  int b = g >> 12;
  int dn = g & 4095;
  float A = -__expf(A_log[dn]);
  int d = dn >> 4;
  float H = 0.f;
  for (int c = 0; c < NCHUNK; ++c) {
    size_t cidx = (size_t)(b*NCHUNK + c)*DI + d;
    size_t idx = cidx*16 + (dn & 15);
    float Sv = S[idx];
    float P = __expf(A * sumdl[cidx]);
    S[idx] = H;
    H = P*H + Sv;
  }
}

// ============ K_C: rmsnorm + in_proj(z) + scan p3 + gate + out_proj + residual ============
// block = (batch, 32-chunk), 1024 threads = 16 waves
__global__ __launch_bounds__(1024) void layer_back(
    const float* __restrict__ src, const float* __restrict__ nw,
    const f16* __restrict__ Win, const f16* __restrict__ xs,
    const float* __restrict__ dbc, const float* __restrict__ A_log,
    const float* __restrict__ dtw, const float* __restrict__ dtb,
    const float* __restrict__ Dp, const float* __restrict__ Hinit,
    const f16* __restrict__ Wo, float* __restrict__ hout)
{
  __shared__ __align__(16) f16 Ah[32][136];
  __shared__ __align__(16) f16 sXs[32][264];
  __shared__ __align__(16) f16 sZ[32][264];
  __shared__ __align__(16) f16 sY[32][264];
  __shared__ __align__(16) float sDbc[32][40];
  const int bc = blockIdx.x;
  const int b = bc >> 5, ck = bc & (NCHUNK-1);
  const int t0 = ck*CHUNK;
  const int tid = threadIdx.x;
  const int l = tid & 63, w = tid >> 6;
  const int fr = l & 15, kg = l >> 4;

  // --- stage Ah with fused rmsnorm: 32 lanes per row ---
  {
    const int r = tid >> 5;            // 0..31
    const int seg = (tid & 31) * 4;
    const float* hr = src + (size_t)(b*LQ + t0 + r)*DM + seg;
    float4 v = *(const float4*)hr;
    float ss = v.x*v.x + v.y*v.y + v.z*v.z + v.w*v.w;
    ss += __shfl_xor(ss, 1); ss += __shfl_xor(ss, 2);
    ss += __shfl_xor(ss, 4); ss += __shfl_xor(ss, 8); ss += __shfl_xor(ss, 16);
    const float sc = rsqrtf(ss*(1.f/128.f) + EPSF);
    float4 wv = *(const float4*)(nw + seg);
    f16x4 o;
    o.x=(f16)(v.x*sc*wv.x); o.y=(f16)(v.y*sc*wv.y);
    o.z=(f16)(v.z*sc*wv.z); o.w=(f16)(v.w*sc*wv.w);
    *(f16x4*)&Ah[r][seg] = o;
  }
  // --- stage xs chunk: 8 f16 per thread ---
  {
    const int r = tid >> 5, col = (tid & 31) * 8;
    *(f16x8*)&sXs[r][col] = *(const f16x8*)(xs + (size_t)(b*LQ + t0 + r)*DI + col);
  }
  // --- stage dbc rows ---
  for (int e = tid; e < 32*40; e += 1024) {
    int t = e / 40, c = e % 40;
    sDbc[t][c] = dbc[(size_t)(b*LQ + t0 + t)*40 + c];
  }
  __syncthreads();

  // --- in_proj z-half MFMA: sZ[32][256]; wave w -> cols w*16..+15 ---
  {
    f32x4 acc[2];
    acc[0] = (f32x4){0.f,0.f,0.f,0.f};
    acc[1] = (f32x4){0.f,0.f,0.f,0.f};
    #pragma unroll
    for (int s = 0; s < 4; ++s) {
      f16x8 bfv = *(const f16x8*)(Win + (size_t)(DI + w*16 + fr)*DM + s*32 + kg*8);
      #pragma unroll
      for (int m = 0; m < 2; ++m) {
        f16x8 afv = *(const f16x8*)&Ah[m*16 + fr][s*32 + kg*8];
        acc[m] = __builtin_amdgcn_mfma_f32_16x16x32_f16(afv, bfv, acc[m], 0, 0, 0);
      }
    }
    #pragma unroll
    for (int m = 0; m < 2; ++m)
      #pragma unroll
      for (int j = 0; j < 4; ++j)
        sZ[m*16 + kg*4 + j][w*16 + fr] = (f16)acc[m][j];
  }

  // --- per-thread scan state: thread = (d, 4-state group g) ---
  const int d = tid >> 2, g = tid & 3;
  float A[4];
  #pragma unroll
  for (int j = 0; j < 4; ++j) A[j] = -__expf(A_log[d*16 + g*4 + j]);
  float h[4];
  {
    float4 hv = *(const float4*)(Hinit + ((size_t)bc*DI + d)*16 + g*4);
    h[0]=hv.x; h[1]=hv.y; h[2]=hv.z; h[3]=hv.w;
  }
  const float4 dw0 = *(const float4*)(dtw + d*8);
  const float4 dw1 = *(const float4*)(dtw + d*8 + 4);
  const float bt = dtb[d];
  const float Dv = Dp[d];

  // --- prefetch out_proj weights (in flight under the scan) ---
  const int mi = w & 1, ni = w >> 1;       // 2 M x 8 N fragments
  f16x8 bf[8];
  #pragma unroll
  for (int s = 0; s < 8; ++s)
    bf[s] = *(const f16x8*)(Wo + (size_t)(ni*16 + fr)*DI + s*32 + kg*8);
  __syncthreads();

  // --- scan p3 + gate -> sY ---
  for (int t = 0; t < CHUNK; ++t) {
    float xa = bt + sDbc[t][0]*dw0.x + sDbc[t][1]*dw0.y + sDbc[t][2]*dw0.z + sDbc[t][3]*dw0.w
                  + sDbc[t][4]*dw1.x + sDbc[t][5]*dw1.y + sDbc[t][6]*dw1.z + sDbc[t][7]*dw1.w;
    float dl = softplus_f(xa);
    float uu = (float)sXs[t][d];
    float du = dl*uu;
    float pacc = 0.f;
    #pragma unroll
    for (int j = 0; j < 4; ++j) {
      h[j] = __expf(dl*A[j])*h[j] + du*sDbc[t][8 + g*4 + j];
      pacc += h[j]*sDbc[t][24 + g*4 + j];
    }
    pacc += __shfl_xor(pacc, 1);
    pacc += __shfl_xor(pacc, 2);
    if (g == 0) {
      float res = (float)sZ[t][d];
      sY[t][d] = (f16)((pacc + uu*Dv) * (res * sigmoid_f(res)));
    }
  }
  __syncthreads();

  // --- out_proj MFMA: y(32x256) @ Wo(128x256)^T + residual; wave w = (mi, ni) frag ---
  {
    f32x4 acc = (f32x4){0.f,0.f,0.f,0.f};
    #pragma unroll
    for (int s = 0; s < 8; ++s) {
      f16x8 afv = *(const f16x8*)&sY[mi*16 + fr][s*32 + kg*8];
      acc = __builtin_amdgcn_mfma_f32_16x16x32_f16(afv, bf[s], acc, 0, 0, 0);
    }
    const int col = ni*16 + fr;
    #pragma unroll
    for (int j = 0; j < 4; ++j) {
      const int row = mi*16 + kg*4 + j;
      const size_t gi = (size_t)(b*LQ + t0 + row)*DM + col;
      hout[gi] = acc[j] + src[gi];
    }
  }
}

// ---------------- final: last-token rmsnorm + batchnorm + relu + head ----------------
__global__ __launch_bounds__(256) void final_kernel(const float* __restrict__ h,
    const float* __restrict__ nfw, const float* __restrict__ gamma, const float* __restrict__ beta,
    const float* __restrict__ hw, const float* __restrict__ hb, float* __restrict__ out) {
  __shared__ float sf[8][128];
  __shared__ float sscale[8];
  int tid = threadIdx.x;
  for (int e = tid; e < 1024; e += 256) {
    int b = e >> 7, dd = e & 127;
    sf[b][dd] = h[((size_t)b*LQ + (LQ-1))*DM + dd];
  }
  __syncthreads();
  if (tid < 8) {
    float ss = 0.f;
    for (int dd = 0; dd < 128; ++dd) { float v = sf[tid][dd]; ss += v*v; }
    sscale[tid] = rsqrtf(ss/128.f + EPSF);
  }
  __syncthreads();
  for (int e = tid; e < 1024; e += 256) {
    int b = e >> 7, dd = e & 127;
    sf[b][dd] = sf[b][dd]*sscale[b]*nfw[dd];
  }
  __syncthreads();
  if (tid < 128) {
    float mu = 0.f;
    for (int b = 0; b < 8; ++b) mu += sf[b][tid];
    mu *= 0.125f;
    float var = 0.f;
    for (int b = 0; b < 8; ++b) { float dv = sf[b][tid]-mu; var += dv*dv; }
    var *= 0.125f;
    float rs = rsqrtf(var + EPSF);
    for (int b = 0; b < 8; ++b) {
      float v = (sf[b][tid]-mu)*rs*gamma[tid] + beta[tid];
      sf[b][tid] = v > 0.f ? v : 0.f;
    }
  }
  __syncthreads();
  if (tid < 16) {
    int b = tid >> 1, s = tid & 1;
    float acc = hb[s];
    for (int dd = 0; dd < 128; ++dd) acc += sf[b][dd]*hw[s*128+dd];
    out[b*2+s] = acc;
  }
}

extern "C" void kernel_launch(void* const* d_in, const int* in_sizes, int n_in,
                              void* d_out, int out_size, void* d_ws, size_t ws_size,
                              hipStream_t stream) {
  const float* x      = (const float*)d_in[0];
  const float* in_w   = (const float*)d_in[1];
  const float* conv_w = (const float*)d_in[2];
  const float* conv_b = (const float*)d_in[3];
  const float* xp_w   = (const float*)d_in[4];
  const float* dt_w   = (const float*)d_in[5];
  const float* dt_b   = (const float*)d_in[6];
  const float* A_log  = (const float*)d_in[7];
  const float* Dp     = (const float*)d_in[8];
  const float* out_w  = (const float*)d_in[9];
  const float* norm_w = (const float*)d_in[10];
  const float* norm_f = (const float*)d_in[11];
  const float* gamma  = (const float*)d_in[12];
  const float* beta   = (const float*)d_in[13];
  const float* head_w = (const float*)d_in[14];
  const float* head_b = (const float*)d_in[15];

  float* ws = (float*)d_ws;
  float* h     = ws;                             // ROWS*DM fp32
  float* dbc   = h + (size_t)ROWS*DM;            // ROWS*40 fp32
  float* S     = dbc + (size_t)ROWS*40;          // NB*NCHUNK*DI*16 fp32
  float* sumdl = S + (size_t)NB*NCHUNK*DI*16;    // NB*NCHUNK*DI fp32
  f16* xs     = (f16*)(sumdl + (size_t)NB*NCHUNK*DI); // ROWS*256 f16
  f16* wf_in  = xs + (size_t)ROWS*DI;                 // 4*512*128 f16
  f16* wf_xp  = wf_in + (size_t)4*2*DI*DM;            // 4*40*256 f16
  f16* wf_out = wf_xp + (size_t)4*40*DI;              // 4*128*256 f16

  cvt_all<<<424, 256, 0, stream>>>(in_w, xp_w, out_w, wf_in, wf_xp, wf_out);

  for (int layer = 0; layer < 4; ++layer) {
    const float* src = layer ? h : x;
    layer_front<<<NB*NCHUNK, 1024, 0, stream>>>(
        src, norm_w + (size_t)layer*DM, wf_in + (size_t)layer*2*DI*DM,
        conv_w + (size_t)layer*DI*4, conv_b + (size_t)layer*DI,
        wf_xp + (size_t)layer*40*DI, A_log + (size_t)layer*DI*DSN,
        dt_w + (size_t)layer*DI*8, dt_b + (size_t)layer*DI,
        xs, dbc, S, sumdl);
    scan_p2<<<NB*DI*DSN/256, 256, 0, stream>>>(S, sumdl, A_log + (size_t)layer*DI*DSN);
    layer_back<<<NB*NCHUNK, 1024, 0, stream>>>(
        src, norm_w + (size_t)layer*DM, wf_in + (size_t)layer*2*DI*DM,
        xs, dbc, A_log + (size_t)layer*DI*DSN,
        dt_w + (size_t)layer*DI*8, dt_b + (size_t)layer*DI,
        Dp + (size_t)layer*DI, S,
        wf_out + (size_t)layer*DM*DI, h);
  }
  final_kernel<<<1, 256, 0, stream>>>(h, norm_f, gamma, beta, head_w, head_b, (float*)d_out);
}

// Round 7
// 285.278 us; speedup vs baseline: 1.4087x; 1.4087x over previous
//
#include <hip/hip_runtime.h>
#include <cstddef>

#define LQ 1024
#define DM 128
#define DI 256
#define DSN 16
#define NB 8
#define ROWS (NB*LQ)
#define EPSF 1e-5f
#define CHUNK 16
#define NCHUNK (LQ/CHUNK)

typedef _Float16 f16;
typedef __attribute__((ext_vector_type(8))) _Float16 f16x8;
typedef __attribute__((ext_vector_type(4))) _Float16 f16x4;
typedef __attribute__((ext_vector_type(4))) float f32x4;

static __device__ __forceinline__ float sigmoid_f(float x) { return 1.f/(1.f+__expf(-x)); }
static __device__ __forceinline__ float softplus_f(float x) {
  return (x > 20.f) ? x : log1pf(__expf(x));
}

// ---------------- one-shot fp32 -> fp16 conversion of all three weight sets ----------------
__global__ __launch_bounds__(256) void cvt_all(
    const float* __restrict__ a, const float* __restrict__ bsrc, const float* __restrict__ csrc,
    f16* __restrict__ oa, f16* __restrict__ ob, f16* __restrict__ oc)
{
  int i = blockIdx.x*256 + threadIdx.x;
  const int na = (4*2*DI*DM)/4;
  const int nb = (4*40*DI)/4;
  const int nc = (4*DM*DI)/4;
  const float* s; f16* o; int k;
  if (i < na)            { s = a;    o = oa; k = i; }
  else if (i < na+nb)    { s = bsrc; o = ob; k = i - na; }
  else if (i < na+nb+nc) { s = csrc; o = oc; k = i - na - nb; }
  else return;
  float4 v = ((const float4*)s)[k];
  f16x4 r; r.x=(f16)v.x; r.y=(f16)v.y; r.z=(f16)v.z; r.w=(f16)v.w;
  ((f16x4*)o)[k] = r;
}

// ============ K1: fused rmsnorm + in_proj GEMM (M=64,N=64,K=128) -> xz ============
__global__ __launch_bounds__(256) void norm_inproj(
    const float* __restrict__ hin, const float* __restrict__ nw,
    const f16* __restrict__ Wf, f16* __restrict__ xz)
{
  __shared__ __align__(16) f16 Alds[64][136];
  __shared__ __align__(16) f16 Blds[64][136];
  const int tid = threadIdx.x;
  const int row0 = blockIdx.x*64, col0 = blockIdx.y*64;
  #pragma unroll
  for (int cc = tid; cc < 1024; cc += 256) {
    int r = cc >> 4, off = (cc & 15) << 3;
    *(f16x8*)&Blds[r][off] = *(const f16x8*)(Wf + (size_t)(col0 + r)*DM + off);
  }
  {
    const int r = tid >> 2, seg = (tid & 3) * 32;
    const float* hr = hin + (size_t)(row0 + r)*DM + seg;
    float4 v[8];
    float ss = 0.f;
    #pragma unroll
    for (int j = 0; j < 8; ++j) {
      v[j] = *(const float4*)(hr + j*4);
      ss += v[j].x*v[j].x + v[j].y*v[j].y + v[j].z*v[j].z + v[j].w*v[j].w;
    }
    ss += __shfl_xor(ss, 1);
    ss += __shfl_xor(ss, 2);
    const float sc = rsqrtf(ss*(1.f/128.f) + EPSF);
    #pragma unroll
    for (int j = 0; j < 8; ++j) {
      float4 wv = *(const float4*)(nw + seg + j*4);
      f16x4 o;
      o.x = (f16)(v[j].x*sc*wv.x);
      o.y = (f16)(v[j].y*sc*wv.y);
      o.z = (f16)(v[j].z*sc*wv.z);
      o.w = (f16)(v[j].w*sc*wv.w);
      *(f16x4*)&Alds[r][seg + j*4] = o;
    }
  }
  __syncthreads();
  const int l = tid & 63, w = tid >> 6;
  const int wr = w >> 1, wc = w & 1;
  const int fr = l & 15, kg = l >> 4;
  f16x8 af[2][4], bf[2][4];
  #pragma unroll
  for (int m = 0; m < 2; ++m)
    #pragma unroll
    for (int s = 0; s < 4; ++s)
      af[m][s] = *(const f16x8*)&Alds[wr*32 + m*16 + fr][s*32 + kg*8];
  #pragma unroll
  for (int n = 0; n < 2; ++n)
    #pragma unroll
    for (int s = 0; s < 4; ++s)
      bf[n][s] = *(const f16x8*)&Blds[wc*32 + n*16 + fr][s*32 + kg*8];
  f32x4 acc[2][2];
  #pragma unroll
  for (int m = 0; m < 2; ++m)
    #pragma unroll
    for (int n = 0; n < 2; ++n)
      acc[m][n] = (f32x4){0.f,0.f,0.f,0.f};
  #pragma unroll
  for (int s = 0; s < 4; ++s)
    #pragma unroll
    for (int m = 0; m < 2; ++m)
      #pragma unroll
      for (int n = 0; n < 2; ++n)
        acc[m][n] = __builtin_amdgcn_mfma_f32_16x16x32_f16(af[m][s], bf[n][s], acc[m][n], 0, 0, 0);
  #pragma unroll
  for (int m = 0; m < 2; ++m)
    #pragma unroll
    for (int n = 0; n < 2; ++n) {
      const int col = col0 + wc*32 + n*16 + fr;
      #pragma unroll
      for (int j = 0; j < 4; ++j) {
        const int row = row0 + wr*32 + m*16 + kg*4 + j;
        xz[(size_t)row*(2*DI) + col] = (f16)acc[m][n][j];
      }
    }
}

// ============ K2: conv+silu + x_proj + scan p1 (block = batch x 16-chunk, 256 thr) ============
__global__ __launch_bounds__(256) void layer_front(
    const f16* __restrict__ xz, const float* __restrict__ cw, const float* __restrict__ cb,
    const f16* __restrict__ xpw, const float* __restrict__ A_log,
    const float* __restrict__ dtw, const float* __restrict__ dtb,
    f16* __restrict__ xs_out, float* __restrict__ dbc_out,
    float* __restrict__ S, float* __restrict__ sumdl_out)
{
  __shared__ __align__(16) f16 sXz[19][264];     // halo x-part rows t0-3..t0+15
  __shared__ __align__(16) f16 sXs[16][264];
  __shared__ __align__(16) float sDbc[16][40];
  const int bc = blockIdx.x;
  const int b = bc >> 6, ck = bc & (NCHUNK-1);
  const int t0 = ck*CHUNK;
  const int tid = threadIdx.x;
  const int l = tid & 63, w = tid >> 6;
  const int fr = l & 15, kg = l >> 4;

  // stage halo xz x-half: 19 rows x 256 f16
  for (int e = tid; e < 19*32; e += 256) {
    int r = e >> 5, off = (e & 31) << 3;
    f16x8 v = (f16x8){0,0,0,0,0,0,0,0};
    if (ck > 0 || r >= 3)
      v = *(const f16x8*)(xz + (size_t)(b*LQ + t0 - 3 + r)*(2*DI) + off);
    *(f16x8*)&sXz[r][off] = v;
  }
  __syncthreads();

  // conv + silu (thread = channel), 16 steps
  {
    const int d = tid;
    const float4 cwv = *(const float4*)(cw + d*4);
    const float bias = cb[d];
    #pragma unroll 4
    for (int t = 0; t < CHUNK; ++t) {
      float a = bias + (float)sXz[t][d]*cwv.x + (float)sXz[t+1][d]*cwv.y
                     + (float)sXz[t+2][d]*cwv.z + (float)sXz[t+3][d]*cwv.w;
      float sv = a * sigmoid_f(a);
      f16 s16 = (f16)sv;
      sXs[t][d] = s16;
      xs_out[(size_t)(b*LQ + t0 + t)*DI + d] = s16;
    }
  }
  __syncthreads();

  // x_proj MFMA: dbc[16][40] = xs(16x256) @ xpw(40x256)^T; waves 0..2, one 16-col frag each
  if (w < 3) {
    const int col = w*16 + fr;
    f32x4 acc = (f32x4){0.f,0.f,0.f,0.f};
    #pragma unroll
    for (int s = 0; s < 8; ++s) {
      f16x8 bfv = (f16x8){0,0,0,0,0,0,0,0};
      if (col < 40) bfv = *(const f16x8*)(xpw + (size_t)col*DI + s*32 + kg*8);
      f16x8 afv = *(const f16x8*)&sXs[fr][s*32 + kg*8];
      acc = __builtin_amdgcn_mfma_f32_16x16x32_f16(afv, bfv, acc, 0, 0, 0);
    }
    if (col < 40) {
      #pragma unroll
      for (int j = 0; j < 4; ++j) {
        int row = kg*4 + j;
        sDbc[row][col] = acc[j];
        dbc_out[(size_t)(b*LQ + t0 + row)*40 + col] = acc[j];
      }
    }
  }
  __syncthreads();

  // scan p1 (thread = channel, 16 states in registers)
  {
    const int d = tid;
    float A[16];
    #pragma unroll
    for (int n = 0; n < 16; ++n) A[n] = -__expf(A_log[d*16+n]);
    const float4 dw0 = *(const float4*)(dtw + d*8);
    const float4 dw1 = *(const float4*)(dtw + d*8 + 4);
    const float bt = dtb[d];
    float h[16] = {};
    float sdl = 0.f;
    for (int t = 0; t < CHUNK; ++t) {
      float xa = bt + sDbc[t][0]*dw0.x + sDbc[t][1]*dw0.y + sDbc[t][2]*dw0.z + sDbc[t][3]*dw0.w
                    + sDbc[t][4]*dw1.x + sDbc[t][5]*dw1.y + sDbc[t][6]*dw1.z + sDbc[t][7]*dw1.w;
      float dl = softplus_f(xa);
      float du = dl * (float)sXs[t][d];
      sdl += dl;
      #pragma unroll
      for (int n = 0; n < 16; ++n)
        h[n] = __expf(dl*A[n])*h[n] + du*sDbc[t][8+n];
    }
    float* Sp = S + ((size_t)bc*DI + d)*16;
    #pragma unroll
    for (int n = 0; n < 16; n += 4)
      *(float4*)(Sp+n) = make_float4(h[n],h[n+1],h[n+2],h[n+3]);
    sumdl_out[(size_t)bc*DI + d] = sdl;
  }
}

// ============ K3: exclusive scan over chunks (in-place S -> Hinit) ============
__global__ __launch_bounds__(256) void scan_p2(
    float* __restrict__ S, const float* __restrict__ sumdl,
    const float* __restrict__ A_log)
{
  int g = blockIdx.x*256 + threadIdx.x;   // b*4096 + d*16 + n
  int b = g >> 12;
  int dn = g & 4095;
  float A = -__expf(A_log[dn]);
  int d = dn >> 4;
  float H = 0.f;
  for (int c = 0; c < NCHUNK; ++c) {
    size_t cidx = (size_t)(b*NCHUNK + c)*DI + d;
    size_t idx = cidx*16 + (dn & 15);
    float Sv = S[idx];
    float P = __expf(A * sumdl[cidx]);
    S[idx] = H;
    H = P*H + Sv;
  }
}

// ============ K4: scan p3 + gate + out_proj + residual (block = batch x 16-chunk, 256 thr) ============
__global__ __launch_bounds__(256) void layer_back(
    const f16* __restrict__ xs, const float* __restrict__ dbc,
    const float* __restrict__ A_log, const float* __restrict__ dtw,
    const float* __restrict__ dtb, const float* __restrict__ Dp,
    const float* __restrict__ Hinit, const f16* __restrict__ xz,
    const f16* __restrict__ Wo, const float* __restrict__ addsrc,
    float* __restrict__ hout)
{
  __shared__ __align__(16) f16 sXs[16][264];
  __shared__ __align__(16) f16 sZ[16][264];
  __shared__ __align__(16) f16 sY[16][264];
  __shared__ __align__(16) float sDbc[16][40];
  const int bc = blockIdx.x;
  const int b = bc >> 6, ck = bc & (NCHUNK-1);
  const int t0 = ck*CHUNK;
  const int tid = threadIdx.x;
  const int l = tid & 63, w = tid >> 6;
  const int fr = l & 15, kg = l >> 4;

  // stage xs and z (res) chunks: 16x256 f16 each; thread: r=tid>>4, col=(tid&15)*16
  {
    const int r = tid >> 4, col = (tid & 15) * 16;
    *(f16x8*)&sXs[r][col]   = *(const f16x8*)(xs + (size_t)(b*LQ + t0 + r)*DI + col);
    *(f16x8*)&sXs[r][col+8] = *(const f16x8*)(xs + (size_t)(b*LQ + t0 + r)*DI + col + 8);
    *(f16x8*)&sZ[r][col]    = *(const f16x8*)(xz + (size_t)(b*LQ + t0 + r)*(2*DI) + DI + col);
    *(f16x8*)&sZ[r][col+8]  = *(const f16x8*)(xz + (size_t)(b*LQ + t0 + r)*(2*DI) + DI + col + 8);
  }
  // stage dbc
  for (int e = tid; e < 16*40; e += 256) {
    int t = e / 40, c = e % 40;
    sDbc[t][c] = dbc[(size_t)(b*LQ + t0 + t)*40 + c];
  }

  // per-thread scan constants + Hinit
  const int d = tid;
  float A[16];
  #pragma unroll
  for (int n = 0; n < 16; ++n) A[n] = -__expf(A_log[d*16+n]);
  float h[16];
  {
    const float* Hp = Hinit + ((size_t)bc*DI + d)*16;
    #pragma unroll
    for (int n = 0; n < 16; n += 4) {
      float4 v = *(const float4*)(Hp+n);
      h[n]=v.x; h[n+1]=v.y; h[n+2]=v.z; h[n+3]=v.w;
    }
  }
  const float4 dw0 = *(const float4*)(dtw + d*8);
  const float4 dw1 = *(const float4*)(dtw + d*8 + 4);
  const float bt = dtb[d];
  const float Dv = Dp[d];

  // prefetch out_proj weight fragments (2 col-frags x 8 k-frags per wave) before the scan
  f16x8 bf[2][8];
  #pragma unroll
  for (int n = 0; n < 2; ++n)
    #pragma unroll
    for (int s = 0; s < 8; ++s)
      bf[n][s] = *(const f16x8*)(Wo + (size_t)(w*32 + n*16 + fr)*DI + s*32 + kg*8);
  __syncthreads();

  // scan p3 + gate -> sY
  for (int t = 0; t < CHUNK; ++t) {
    float xa = bt + sDbc[t][0]*dw0.x + sDbc[t][1]*dw0.y + sDbc[t][2]*dw0.z + sDbc[t][3]*dw0.w
                  + sDbc[t][4]*dw1.x + sDbc[t][5]*dw1.y + sDbc[t][6]*dw1.z + sDbc[t][7]*dw1.w;
    float dl = softplus_f(xa);
    float uu = (float)sXs[t][d];
    float du = dl*uu;
    float pacc = uu*Dv;
    #pragma unroll
    for (int n = 0; n < 16; ++n) {
      h[n] = __expf(dl*A[n])*h[n] + du*sDbc[t][8+n];
      pacc += h[n]*sDbc[t][24+n];
    }
    float res = (float)sZ[t][d];
    sY[t][d] = (f16)(pacc * (res * sigmoid_f(res)));
  }
  __syncthreads();

  // out_proj MFMA: y(16x256) @ Wo(128x256)^T + residual; wave w -> cols w*32..+31
  {
    f32x4 acc[2];
    acc[0] = (f32x4){0.f,0.f,0.f,0.f};
    acc[1] = (f32x4){0.f,0.f,0.f,0.f};
    #pragma unroll
    for (int s = 0; s < 8; ++s) {
      f16x8 afv = *(const f16x8*)&sY[fr][s*32 + kg*8];
      #pragma unroll
      for (int n = 0; n < 2; ++n)
        acc[n] = __builtin_amdgcn_mfma_f32_16x16x32_f16(afv, bf[n][s], acc[n], 0, 0, 0);
    }
    #pragma unroll
    for (int n = 0; n < 2; ++n) {
      const int col = w*32 + n*16 + fr;
      #pragma unroll
      for (int j = 0; j < 4; ++j) {
        const int row = kg*4 + j;
        const size_t gi = (size_t)(b*LQ + t0 + row)*DM + col;
        hout[gi] = acc[n][j] + addsrc[gi];
      }
    }
  }
}

// ---------------- final: last-token rmsnorm + batchnorm + relu + head ----------------
__global__ __launch_bounds__(256) void final_kernel(const float* __restrict__ h,
    const float* __restrict__ nfw, const float* __restrict__ gamma, const float* __restrict__ beta,
    const float* __restrict__ hw, const float* __restrict__ hb, float* __restrict__ out) {
  __shared__ float sf[8][128];
  __shared__ float sscale[8];
  int tid = threadIdx.x;
  for (int e = tid; e < 1024; e += 256) {
    int b = e >> 7, dd = e & 127;
    sf[b][dd] = h[((size_t)b*LQ + (LQ-1))*DM + dd];
  }
  __syncthreads();
  if (tid < 8) {
    float ss = 0.f;
    for (int dd = 0; dd < 128; ++dd) { float v = sf[tid][dd]; ss += v*v; }
    sscale[tid] = rsqrtf(ss/128.f + EPSF);
  }
  __syncthreads();
  for (int e = tid; e < 1024; e += 256) {
    int b = e >> 7, dd = e & 127;
    sf[b][dd] = sf[b][dd]*sscale[b]*nfw[dd];
  }
  __syncthreads();
  if (tid < 128) {
    float mu = 0.f;
    for (int b = 0; b < 8; ++b) mu += sf[b][tid];
    mu *= 0.125f;
    float var = 0.f;
    for (int b = 0; b < 8; ++b) { float dv = sf[b][tid]-mu; var += dv*dv; }
    var *= 0.125f;
    float rs = rsqrtf(var + EPSF);
    for (int b = 0; b < 8; ++b) {
      float v = (sf[b][tid]-mu)*rs*gamma[tid] + beta[tid];
      sf[b][tid] = v > 0.f ? v : 0.f;
    }
  }
  __syncthreads();
  if (tid < 16) {
    int b = tid >> 1, s = tid & 1;
    float acc = hb[s];
    for (int dd = 0; dd < 128; ++dd) acc += sf[b][dd]*hw[s*128+dd];
    out[b*2+s] = acc;
  }
}

extern "C" void kernel_launch(void* const* d_in, const int* in_sizes, int n_in,
                              void* d_out, int out_size, void* d_ws, size_t ws_size,
                              hipStream_t stream) {
  const float* x      = (const float*)d_in[0];
  const float* in_w   = (const float*)d_in[1];
  const float* conv_w = (const float*)d_in[2];
  const float* conv_b = (const float*)d_in[3];
  const float* xp_w   = (const float*)d_in[4];
  const float* dt_w   = (const float*)d_in[5];
  const float* dt_b   = (const float*)d_in[6];
  const float* A_log  = (const float*)d_in[7];
  const float* Dp     = (const float*)d_in[8];
  const float* out_w  = (const float*)d_in[9];
  const float* norm_w = (const float*)d_in[10];
  const float* norm_f = (const float*)d_in[11];
  const float* gamma  = (const float*)d_in[12];
  const float* beta   = (const float*)d_in[13];
  const float* head_w = (const float*)d_in[14];
  const float* head_b = (const float*)d_in[15];

  float* ws = (float*)d_ws;
  float* h     = ws;                             // ROWS*DM fp32
  float* dbc   = h + (size_t)ROWS*DM;            // ROWS*40 fp32
  float* S     = dbc + (size_t)ROWS*40;          // NB*NCHUNK*DI*16 fp32 (8 MB)
  float* sumdl = S + (size_t)NB*NCHUNK*DI*16;    // NB*NCHUNK*DI fp32
  f16* xz     = (f16*)(sumdl + (size_t)NB*NCHUNK*DI); // ROWS*512 f16
  f16* xs     = xz + (size_t)ROWS*2*DI;               // ROWS*256 f16
  f16* wf_in  = xs + (size_t)ROWS*DI;                 // 4*512*128 f16
  f16* wf_xp  = wf_in + (size_t)4*2*DI*DM;            // 4*40*256 f16
  f16* wf_out = wf_xp + (size_t)4*40*DI;              // 4*128*256 f16

  cvt_all<<<424, 256, 0, stream>>>(in_w, xp_w, out_w, wf_in, wf_xp, wf_out);

  for (int layer = 0; layer < 4; ++layer) {
    const float* src = layer ? h : x;   // rmsnorm input and residual source
    norm_inproj<<<dim3(ROWS/64, 8), 256, 0, stream>>>(
        src, norm_w + (size_t)layer*DM, wf_in + (size_t)layer*2*DI*DM, xz);
    layer_front<<<NB*NCHUNK, 256, 0, stream>>>(
        xz, conv_w + (size_t)layer*DI*4, conv_b + (size_t)layer*DI,
        wf_xp + (size_t)layer*40*DI, A_log + (size_t)layer*DI*DSN,
        dt_w + (size_t)layer*DI*8, dt_b + (size_t)layer*DI,
        xs, dbc, S, sumdl);
    scan_p2<<<NB*DI*DSN/256, 256, 0, stream>>>(S, sumdl, A_log + (size_t)layer*DI*DSN);
    layer_back<<<NB*NCHUNK, 256, 0, stream>>>(
        xs, dbc, A_log + (size_t)layer*DI*DSN, dt_w + (size_t)layer*DI*8,
        dt_b + (size_t)layer*DI, Dp + (size_t)layer*DI, S, xz,
        wf_out + (size_t)layer*DM*DI, src, h);
  }
  final_kernel<<<1, 256, 0, stream>>>(h, norm_f, gamma, beta, head_w, head_b, (float*)d_out);
}

// Round 9
// 261.505 us; speedup vs baseline: 1.5368x; 1.0909x over previous
//
#include <hip/hip_runtime.h>
#include <cstddef>

#define LQ 1024
#define DM 128
#define DI 256
#define DSN 16
#define NB 8
#define ROWS (NB*LQ)
#define EPSF 1e-5f
#define CHUNK 16
#define NCHUNK (LQ/CHUNK)   // 64
#define NBLK (NB*NCHUNK)    // 512

typedef _Float16 f16;
typedef __attribute__((ext_vector_type(8))) _Float16 f16x8;
typedef __attribute__((ext_vector_type(4))) _Float16 f16x4;
typedef __attribute__((ext_vector_type(4))) float f32x4;

static __device__ __forceinline__ float sigmoid_f(float x) { return 1.f/(1.f+__expf(-x)); }
static __device__ __forceinline__ float softplus_f(float x) {
  return (x > 20.f) ? x : log1pf(__expf(x));
}

// ---------------- one-shot fp32 -> fp16 conversion of all three weight sets ----------------
__global__ __launch_bounds__(256) void cvt_all(
    const float* __restrict__ a, const float* __restrict__ bsrc, const float* __restrict__ csrc,
    f16* __restrict__ oa, f16* __restrict__ ob, f16* __restrict__ oc)
{
  int i = blockIdx.x*256 + threadIdx.x;
  const int na = (4*2*DI*DM)/4;
  const int nb = (4*40*DI)/4;
  const int nc = (4*DM*DI)/4;
  const float* s; f16* o; int k;
  if (i < na)            { s = a;    o = oa; k = i; }
  else if (i < na+nb)    { s = bsrc; o = ob; k = i - na; }
  else if (i < na+nb+nc) { s = csrc; o = oc; k = i - na - nb; }
  else return;
  float4 v = ((const float4*)s)[k];
  f16x4 r; r.x=(f16)v.x; r.y=(f16)v.y; r.z=(f16)v.z; r.w=(f16)v.w;
  ((f16x4*)o)[k] = r;
}

// ============ K_A: rmsnorm(halo) + in_proj(x-half) + conv/silu + x_proj + scan p1 ============
// block = (batch, 16-chunk), 256 threads = 4 waves; 512 blocks
__global__ __launch_bounds__(256) void layer_front(
    const float* __restrict__ src, const float* __restrict__ nw,
    const f16* __restrict__ Win,                      // [512][128] f16 (x rows 0..255)
    const float* __restrict__ cw, const float* __restrict__ cb,
    const f16* __restrict__ xpw,                      // [40][256] f16
    const float* __restrict__ A_log,
    const float* __restrict__ dtw, const float* __restrict__ dtb,
    f16* __restrict__ xs_out, float* __restrict__ dbc_out,
    float* __restrict__ S, float* __restrict__ sumdl_out)
{
  __shared__ __align__(16) f16 Ah[19][136];     // rmsnorm'd rows t0-3 .. t0+15
  __shared__ __align__(16) f16 sXc[19][264];    // in_proj x output (conv input)
  __shared__ __align__(16) f16 sXs[16][264];    // conv+silu output
  __shared__ __align__(16) float sDbc[16][40];
  const int bc = blockIdx.x;
  const int b = bc >> 6, ck = bc & (NCHUNK-1);
  const int t0 = ck*CHUNK;
  const int tid = threadIdx.x;
  const int l = tid & 63, w = tid >> 6;
  const int fr = l & 15, kg = l >> 4;

  // --- stage Ah rows 0..18 (global t0-3..t0+15), fused rmsnorm: 8 lanes per row ---
  {
    const int r = tid >> 3;             // 0..31
    const int seg = (tid & 7) * 16;
    const bool valid = (r < 19) && (ck > 0 || r >= 3);
    float4 v[4];
    float ss = 0.f;
    if (valid) {
      const float* hr = src + (size_t)(b*LQ + t0 - 3 + r)*DM + seg;
      #pragma unroll
      for (int j = 0; j < 4; ++j) {
        v[j] = *(const float4*)(hr + j*4);
        ss += v[j].x*v[j].x + v[j].y*v[j].y + v[j].z*v[j].z + v[j].w*v[j].w;
      }
    }
    ss += __shfl_xor(ss, 1); ss += __shfl_xor(ss, 2); ss += __shfl_xor(ss, 4);
    if (r < 19) {
      if (valid) {
        const float sc = rsqrtf(ss*(1.f/128.f) + EPSF);
        #pragma unroll
        for (int j = 0; j < 4; ++j) {
          float4 wv = *(const float4*)(nw + seg + j*4);
          f16x4 o;
          o.x=(f16)(v[j].x*sc*wv.x); o.y=(f16)(v[j].y*sc*wv.y);
          o.z=(f16)(v[j].z*sc*wv.z); o.w=(f16)(v[j].w*sc*wv.w);
          *(f16x4*)&Ah[r][seg + j*4] = o;
        }
      } else {
        #pragma unroll
        for (int j = 0; j < 4; ++j)
          *(f16x4*)&Ah[r][seg + j*4] = (f16x4){0,0,0,0};
      }
    }
  }
  __syncthreads();

  // --- in_proj x-half MFMA: rows 0..18 via 2 overlapping M-frags; wave w -> cols w*64..+63 ---
  {
    f32x4 ax1[4], ax2[4];
    #pragma unroll
    for (int n = 0; n < 4; ++n) {
      ax1[n] = (f32x4){0.f,0.f,0.f,0.f};
      ax2[n] = (f32x4){0.f,0.f,0.f,0.f};
    }
    #pragma unroll
    for (int s = 0; s < 4; ++s) {
      f16x8 a1 = *(const f16x8*)&Ah[fr][s*32 + kg*8];        // rows 0..15
      f16x8 a2 = *(const f16x8*)&Ah[3 + fr][s*32 + kg*8];    // rows 3..18
      #pragma unroll
      for (int n = 0; n < 4; ++n) {
        f16x8 bx = *(const f16x8*)(Win + (size_t)(w*64 + n*16 + fr)*DM + s*32 + kg*8);
        ax1[n] = __builtin_amdgcn_mfma_f32_16x16x32_f16(a1, bx, ax1[n], 0, 0, 0);
        ax2[n] = __builtin_amdgcn_mfma_f32_16x16x32_f16(a2, bx, ax2[n], 0, 0, 0);
      }
    }
    #pragma unroll
    for (int n = 0; n < 4; ++n) {
      const int col = w*64 + n*16 + fr;
      #pragma unroll
      for (int j = 0; j < 4; ++j)
        sXc[3 + kg*4 + j][col] = (f16)ax2[n][j];
      if (kg == 0) {
        #pragma unroll
        for (int j = 0; j < 3; ++j)
          sXc[j][col] = (f16)ax1[n][j];
      }
    }
  }
  __syncthreads();

  // --- conv + silu (thread = channel); out t uses sXc rows t..t+3 ---
  {
    const int d = tid;
    const float4 cwv = *(const float4*)(cw + d*4);
    const float bias = cb[d];
    #pragma unroll 4
    for (int t = 0; t < CHUNK; ++t) {
      float a = bias + (float)sXc[t][d]*cwv.x + (float)sXc[t+1][d]*cwv.y
                     + (float)sXc[t+2][d]*cwv.z + (float)sXc[t+3][d]*cwv.w;
      float sv = a * sigmoid_f(a);
      f16 s16 = (f16)sv;
      sXs[t][d] = s16;
      xs_out[(size_t)(b*LQ + t0 + t)*DI + d] = s16;
    }
  }
  __syncthreads();

  // --- x_proj MFMA: dbc[16][40]; waves 0..2, one 16-col frag each ---
  if (w < 3) {
    const int col = w*16 + fr;
    f32x4 acc = (f32x4){0.f,0.f,0.f,0.f};
    #pragma unroll
    for (int s = 0; s < 8; ++s) {
      f16x8 bfv = (f16x8){0,0,0,0,0,0,0,0};
      if (col < 40) bfv = *(const f16x8*)(xpw + (size_t)col*DI + s*32 + kg*8);
      f16x8 afv = *(const f16x8*)&sXs[fr][s*32 + kg*8];
      acc = __builtin_amdgcn_mfma_f32_16x16x32_f16(afv, bfv, acc, 0, 0, 0);
    }
    if (col < 40) {
      #pragma unroll
      for (int j = 0; j < 4; ++j) {
        int row = kg*4 + j;
        sDbc[row][col] = acc[j];
        dbc_out[(size_t)(b*LQ + t0 + row)*40 + col] = acc[j];
      }
    }
  }
  __syncthreads();

  // --- scan p1 (thread = channel, 16 states in registers) ---
  {
    const int d = tid;
    float A[16];
    #pragma unroll
    for (int n = 0; n < 16; ++n) A[n] = -__expf(A_log[d*16+n]);
    const float4 dw0 = *(const float4*)(dtw + d*8);
    const float4 dw1 = *(const float4*)(dtw + d*8 + 4);
    const float bt = dtb[d];
    float h[16] = {};
    float sdl = 0.f;
    for (int t = 0; t < CHUNK; ++t) {
      float xa = bt + sDbc[t][0]*dw0.x + sDbc[t][1]*dw0.y + sDbc[t][2]*dw0.z + sDbc[t][3]*dw0.w
                    + sDbc[t][4]*dw1.x + sDbc[t][5]*dw1.y + sDbc[t][6]*dw1.z + sDbc[t][7]*dw1.w;
      float dl = softplus_f(xa);
      float du = dl * (float)sXs[t][d];
      sdl += dl;
      #pragma unroll
      for (int n = 0; n < 16; ++n)
        h[n] = __expf(dl*A[n])*h[n] + du*sDbc[t][8+n];
    }
    float* Sp = S + ((size_t)bc*DI + d)*16;
    #pragma unroll
    for (int n = 0; n < 16; n += 4)
      *(float4*)(Sp+n) = make_float4(h[n],h[n+1],h[n+2],h[n+3]);
    sumdl_out[(size_t)bc*DI + d] = sdl;
  }
}

// ============ K_B: exclusive scan over chunks (in-place S -> Hinit) ============
__global__ __launch_bounds__(256) void scan_p2(
    float* __restrict__ S, const float* __restrict__ sumdl,
    const float* __restrict__ A_log)
{
  int g = blockIdx.x*256 + threadIdx.x;   // b*4096 + d*16 + n
  int b = g >> 12;
  int dn = g & 4095;
  float A = -__expf(A_log[dn]);
  int d = dn >> 4;
  float H = 0.f;
  for (int c = 0; c < NCHUNK; ++c) {
    size_t cidx = (size_t)(b*NCHUNK + c)*DI + d;
    size_t idx = cidx*16 + (dn & 15);
    float Sv = S[idx];
    float P = __expf(A * sumdl[cidx]);
    S[idx] = H;
    H = P*H + Sv;
  }
}

// ============ K_C: rmsnorm + in_proj(z-half) + scan p3 + gate + out_proj + residual ============
// block = (batch, 16-chunk), 256 threads = 4 waves; 512 blocks
__global__ __launch_bounds__(256) void layer_back(
    const float* __restrict__ src, const float* __restrict__ nw,
    const f16* __restrict__ Win,                      // full [512][128]; z rows 256..511
    const f16* __restrict__ xs, const float* __restrict__ dbc,
    const float* __restrict__ A_log, const float* __restrict__ dtw,
    const float* __restrict__ dtb, const float* __restrict__ Dp,
    const float* __restrict__ Hinit, const f16* __restrict__ Wo,
    float* __restrict__ hout)
{
  __shared__ __align__(16) f16 Ah[16][136];
  __shared__ __align__(16) f16 sXs[16][264];
  __shared__ __align__(16) f16 sZ[16][264];
  __shared__ __align__(16) f16 sY[16][264];
  __shared__ __align__(16) float sDbc[16][40];
  const int bc = blockIdx.x;
  const int b = bc >> 6, ck = bc & (NCHUNK-1);
  const int t0 = ck*CHUNK;
  const int tid = threadIdx.x;
  const int l = tid & 63, w = tid >> 6;
  const int fr = l & 15, kg = l >> 4;

  // --- stage xs chunk (coalesced) ---
  {
    const int r = tid >> 4, col = (tid & 15) * 16;
    *(f16x8*)&sXs[r][col]   = *(const f16x8*)(xs + (size_t)(b*LQ + t0 + r)*DI + col);
    *(f16x8*)&sXs[r][col+8] = *(const f16x8*)(xs + (size_t)(b*LQ + t0 + r)*DI + col + 8);
  }
  // --- stage dbc ---
  for (int e = tid; e < 16*40; e += 256) {
    int t = e / 40, c = e % 40;
    sDbc[t][c] = dbc[(size_t)(b*LQ + t0 + t)*40 + c];
  }
  // --- stage Ah rows 0..15 with fused rmsnorm: 16 lanes per row ---
  {
    const int r = tid >> 4;             // 0..15
    const int seg = (tid & 15) * 8;
    const float* hr = src + (size_t)(b*LQ + t0 + r)*DM + seg;
    float4 v0 = *(const float4*)(hr);
    float4 v1 = *(const float4*)(hr + 4);
    float ss = v0.x*v0.x+v0.y*v0.y+v0.z*v0.z+v0.w*v0.w
             + v1.x*v1.x+v1.y*v1.y+v1.z*v1.z+v1.w*v1.w;
    ss += __shfl_xor(ss, 1); ss += __shfl_xor(ss, 2);
    ss += __shfl_xor(ss, 4); ss += __shfl_xor(ss, 8);
    const float sc = rsqrtf(ss*(1.f/128.f) + EPSF);
    float4 w0 = *(const float4*)(nw + seg);
    float4 w1 = *(const float4*)(nw + seg + 4);
    f16x4 o0, o1;
    o0.x=(f16)(v0.x*sc*w0.x); o0.y=(f16)(v0.y*sc*w0.y);
    o0.z=(f16)(v0.z*sc*w0.z); o0.w=(f16)(v0.w*sc*w0.w);
    o1.x=(f16)(v1.x*sc*w1.x); o1.y=(f16)(v1.y*sc*w1.y);
    o1.z=(f16)(v1.z*sc*w1.z); o1.w=(f16)(v1.w*sc*w1.w);
    *(f16x4*)&Ah[r][seg]   = o0;
    *(f16x4*)&Ah[r][seg+4] = o1;
  }
  __syncthreads();

  // --- in_proj z-half MFMA: sZ[16][256]; wave w -> cols w*64..+63 ---
  {
    f32x4 az[4];
    #pragma unroll
    for (int n = 0; n < 4; ++n) az[n] = (f32x4){0.f,0.f,0.f,0.f};
    #pragma unroll
    for (int s = 0; s < 4; ++s) {
      f16x8 a = *(const f16x8*)&Ah[fr][s*32 + kg*8];
      #pragma unroll
      for (int n = 0; n < 4; ++n) {
        f16x8 bz = *(const f16x8*)(Win + (size_t)(DI + w*64 + n*16 + fr)*DM + s*32 + kg*8);
        az[n] = __builtin_amdgcn_mfma_f32_16x16x32_f16(a, bz, az[n], 0, 0, 0);
      }
    }
    #pragma unroll
    for (int n = 0; n < 4; ++n) {
      const int col = w*64 + n*16 + fr;
      #pragma unroll
      for (int j = 0; j < 4; ++j)
        sZ[kg*4 + j][col] = (f16)az[n][j];
    }
  }

  // --- per-thread scan constants + Hinit (independent of sZ; overlaps MFMA) ---
  const int d = tid;
  float A[16];
  #pragma unroll
  for (int n = 0; n < 16; ++n) A[n] = -__expf(A_log[d*16+n]);
  float h[16];
  {
    const float* Hp = Hinit + ((size_t)bc*DI + d)*16;
    #pragma unroll
    for (int n = 0; n < 16; n += 4) {
      float4 v = *(const float4*)(Hp+n);
      h[n]=v.x; h[n+1]=v.y; h[n+2]=v.z; h[n+3]=v.w;
    }
  }
  const float4 dw0 = *(const float4*)(dtw + d*8);
  const float4 dw1 = *(const float4*)(dtw + d*8 + 4);
  const float bt = dtb[d];
  const float Dv = Dp[d];
  // prefetch out_proj weight fragments (fly under the scan)
  f16x8 bf[2][8];
  #pragma unroll
  for (int n = 0; n < 2; ++n)
    #pragma unroll
    for (int s = 0; s < 8; ++s)
      bf[n][s] = *(const f16x8*)(Wo + (size_t)(w*32 + n*16 + fr)*DI + s*32 + kg*8);
  __syncthreads();

  // --- scan p3 + gate -> sY ---
  for (int t = 0; t < CHUNK; ++t) {
    float xa = bt + sDbc[t][0]*dw0.x + sDbc[t][1]*dw0.y + sDbc[t][2]*dw0.z + sDbc[t][3]*dw0.w
                  + sDbc[t][4]*dw1.x + sDbc[t][5]*dw1.y + sDbc[t][6]*dw1.z + sDbc[t][7]*dw1.w;
    float dl = softplus_f(xa);
    float uu = (float)sXs[t][d];
    float du = dl*uu;
    float pacc = uu*Dv;
    #pragma unroll
    for (int n = 0; n < 16; ++n) {
      h[n] = __expf(dl*A[n])*h[n] + du*sDbc[t][8+n];
      pacc += h[n]*sDbc[t][24+n];
    }
    float res = (float)sZ[t][d];
    sY[t][d] = (f16)(pacc * (res * sigmoid_f(res)));
  }
  __syncthreads();

  // --- out_proj MFMA: y(16x256) @ Wo(128x256)^T + residual; wave w -> cols w*32..+31 ---
  {
    f32x4 acc[2];
    acc[0] = (f32x4){0.f,0.f,0.f,0.f};
    acc[1] = (f32x4){0.f,0.f,0.f,0.f};
    #pragma unroll
    for (int s = 0; s < 8; ++s) {
      f16x8 afv = *(const f16x8*)&sY[fr][s*32 + kg*8];
      #pragma unroll
      for (int n = 0; n < 2; ++n)
        acc[n] = __builtin_amdgcn_mfma_f32_16x16x32_f16(afv, bf[n][s], acc[n], 0, 0, 0);
    }
    #pragma unroll
    for (int n = 0; n < 2; ++n) {
      const int col = w*32 + n*16 + fr;
      #pragma unroll
      for (int j = 0; j < 4; ++j) {
        const int row = kg*4 + j;
        const size_t gi = (size_t)(b*LQ + t0 + row)*DM + col;
        hout[gi] = acc[n][j] + src[gi];
      }
    }
  }
}

// ---------------- final: last-token rmsnorm + batchnorm + relu + head ----------------
__global__ __launch_bounds__(256) void final_kernel(const float* __restrict__ h,
    const float* __restrict__ nfw, const float* __restrict__ gamma, const float* __restrict__ beta,
    const float* __restrict__ hw, const float* __restrict__ hb, float* __restrict__ out) {
  __shared__ float sf[8][128];
  __shared__ float sscale[8];
  int tid = threadIdx.x;
  for (int e = tid; e < 1024; e += 256) {
    int b = e >> 7, dd = e & 127;
    sf[b][dd] = h[((size_t)b*LQ + (LQ-1))*DM + dd];
  }
  __syncthreads();
  if (tid < 8) {
    float ss = 0.f;
    for (int dd = 0; dd < 128; ++dd) { float v = sf[tid][dd]; ss += v*v; }
    sscale[tid] = rsqrtf(ss/128.f + EPSF);
  }
  __syncthreads();
  for (int e = tid; e < 1024; e += 256) {
    int b = e >> 7, dd = e & 127;
    sf[b][dd] = sf[b][dd]*sscale[b]*nfw[dd];
  }
  __syncthreads();
  if (tid < 128) {
    float mu = 0.f;
    for (int b = 0; b < 8; ++b) mu += sf[b][tid];
    mu *= 0.125f;
    float var = 0.f;
    for (int b = 0; b < 8; ++b) { float dv = sf[b][tid]-mu; var += dv*dv; }
    var *= 0.125f;
    float rs = rsqrtf(var + EPSF);
    for (int b = 0; b < 8; ++b) {
      float v = (sf[b][tid]-mu)*rs*gamma[tid] + beta[tid];
      sf[b][tid] = v > 0.f ? v : 0.f;
    }
  }
  __syncthreads();
  if (tid < 16) {
    int b = tid >> 1, s = tid & 1;
    float acc = hb[s];
    for (int dd = 0; dd < 128; ++dd) acc += sf[b][dd]*hw[s*128+dd];
    out[b*2+s] = acc;
  }
}

extern "C" void kernel_launch(void* const* d_in, const int* in_sizes, int n_in,
                              void* d_out, int out_size, void* d_ws, size_t ws_size,
                              hipStream_t stream) {
  const float* x      = (const float*)d_in[0];
  const float* in_w   = (const float*)d_in[1];
  const float* conv_w = (const float*)d_in[2];
  const float* conv_b = (const float*)d_in[3];
  const float* xp_w   = (const float*)d_in[4];
  const float* dt_w   = (const float*)d_in[5];
  const float* dt_b   = (const float*)d_in[6];
  const float* A_log  = (const float*)d_in[7];
  const float* Dp     = (const float*)d_in[8];
  const float* out_w  = (const float*)d_in[9];
  const float* norm_w = (const float*)d_in[10];
  const float* norm_f = (const float*)d_in[11];
  const float* gamma  = (const float*)d_in[12];
  const float* beta   = (const float*)d_in[13];
  const float* head_w = (const float*)d_in[14];
  const float* head_b = (const float*)d_in[15];

  float* ws = (float*)d_ws;
  float* h     = ws;                             // ROWS*DM fp32
  float* dbc   = h + (size_t)ROWS*DM;            // ROWS*40 fp32
  float* S     = dbc + (size_t)ROWS*40;          // NB*NCHUNK*DI*16 fp32
  float* sumdl = S + (size_t)NB*NCHUNK*DI*16;    // NB*NCHUNK*DI fp32
  f16* xs     = (f16*)(sumdl + (size_t)NB*NCHUNK*DI); // ROWS*256 f16
  f16* wf_in  = xs + (size_t)ROWS*DI;                 // 4*512*128 f16
  f16* wf_xp  = wf_in + (size_t)4*2*DI*DM;            // 4*40*256 f16
  f16* wf_out = wf_xp + (size_t)4*40*DI;              // 4*128*256 f16

  cvt_all<<<424, 256, 0, stream>>>(in_w, xp_w, out_w, wf_in, wf_xp, wf_out);

  for (int layer = 0; layer < 4; ++layer) {
    const float* src = layer ? h : x;   // rmsnorm input and residual source
    layer_front<<<NBLK, 256, 0, stream>>>(
        src, norm_w + (size_t)layer*DM, wf_in + (size_t)layer*2*DI*DM,
        conv_w + (size_t)layer*DI*4, conv_b + (size_t)layer*DI,
        wf_xp + (size_t)layer*40*DI, A_log + (size_t)layer*DI*DSN,
        dt_w + (size_t)layer*DI*8, dt_b + (size_t)layer*DI,
        xs, dbc, S, sumdl);
    scan_p2<<<NB*DI*DSN/256, 256, 0, stream>>>(S, sumdl, A_log + (size_t)layer*DI*DSN);
    layer_back<<<NBLK, 256, 0, stream>>>(
        src, norm_w + (size_t)layer*DM, wf_in + (size_t)layer*2*DI*DM,
        xs, dbc, A_log + (size_t)layer*DI*DSN,
        dt_w + (size_t)layer*DI*8, dt_b + (size_t)layer*DI,
        Dp + (size_t)layer*DI, S,
        wf_out + (size_t)layer*DM*DI, h);
  }
  final_kernel<<<1, 256, 0, stream>>>(h, norm_f, gamma, beta, head_w, head_b, (float*)d_out);
}